// Round 2
// baseline (331.479 us; speedup 1.0000x reference)
//
#include <hip/hip_runtime.h>
#include <math.h>

// Problem constants: T=4096, N=16, D=512.
#define T_   4096
#define D_   512
#define N_   16
#define ND_  (N_*D_)       // 8192 chains

// Fine segmentation (primary path): 256 segments of 16 steps.
#define SF_   256
#define LF_   16           // T_/SF_
#define SNDF_ (SF_*ND_)    // 2,097,152  -> 3 arrays = 24 MiB workspace

// Coarse segmentation (fallback, round-1 verified): 32 segments of 128.
#define S_   32
#define L_   128
#define SND_ (S_*ND_)      // 262,144    -> 3 arrays = 3 MiB workspace

// c^(2^K) by K squarings.
template <int K>
__device__ __forceinline__ float pow2k(float c) {
    float r = c;
    #pragma unroll
    for (int i = 0; i < K; ++i) r *= r;
    return r;
}

// ---------------------------------------------------------------------------
// K1: per (s,n,d) one pass over its segment with zero-init states:
//   P  = particular ha at segment end     (p' = p + a*(x-p))
//   Q0 = particular hv at segment end     (q' = c*(q + a*e^2), e = x-p)
//   S1 = sum of e_t
// Reconstruction (L-generic given cL = c^L):
//   hv_L = cL*hv0 + Q0 - 2*a*cL*S1*ha0 + cL*(1-cL)*ha0^2
//   ha_L = cL*ha0 + P
// ---------------------------------------------------------------------------
template <int SS, int LL, int SWZ>
__global__ __launch_bounds__(256) void k1_seg(const float* __restrict__ x,
                                              const float* __restrict__ alpha,
                                              float* __restrict__ P,
                                              float* __restrict__ Q0,
                                              float* __restrict__ S1) {
    int bid  = blockIdx.x;
    int obid = (bid & 7) * SWZ + (bid >> 3);      // XCD swizzle (bijective)
    int gid  = obid * 256 + threadIdx.x;          // [0, SS*ND_)
    int d    = gid & (D_ - 1);
    int nd   = gid & (ND_ - 1);
    int s    = gid >> 13;                         // / ND_
    float a  = alpha[nd];
    float c  = 1.0f - a;
    float p = 0.0f, q = 0.0f, s1 = 0.0f;
    const float* xp = x + (size_t)s * LL * D_ + d;
    #pragma unroll 8
    for (int t = 0; t < LL; ++t) {
        float xv = xp[(size_t)t * D_];
        float e  = xv - p;
        q  = c * fmaf(a, e * e, q);
        p  = fmaf(a, e, p);
        s1 += e;
    }
    P[gid]  = p;
    Q0[gid] = q;
    S1[gid] = s1;
}

// ---------------------------------------------------------------------------
// K2: per (n,d) scan across segments for BOTH ha and hv; overwrites P with
// segment-start ha and Q0 with segment-start hv; writes finals.
// ---------------------------------------------------------------------------
template <int SS, int LOG2L>
__global__ __launch_bounds__(256) void k2_prefix(const float* __restrict__ h_a,
                                                 const float* __restrict__ h_s,
                                                 const float* __restrict__ alpha,
                                                 float* __restrict__ P,    // -> haStart
                                                 float* __restrict__ Q0,   // -> hvStart
                                                 const float* __restrict__ S1,
                                                 float* __restrict__ out_ha_final,
                                                 float* __restrict__ out_hs_final) {
    int nd   = blockIdx.x * 256 + threadIdx.x;    // [0, ND_)
    float a  = alpha[nd];
    float c  = 1.0f - a;
    float cL = pow2k<LOG2L>(c);
    float k1 = 2.0f * a * cL;
    float k2 = cL * (1.0f - cL);
    float H  = h_a[nd];
    float hs = h_s[nd];
    float V  = hs * hs;
    #pragma unroll 4
    for (int s = 0; s < SS; ++s) {
        size_t i = (size_t)s * ND_ + nd;
        float p  = P[i];
        float q  = Q0[i];
        float s1 = S1[i];
        P[i]  = H;
        Q0[i] = V;
        float Vn = cL * V + q - k1 * s1 * H + k2 * H * H;
        V = fmaxf(Vn, 0.0f);                      // guard cancellation (hv >= 0)
        H = fmaf(cL, H, p);
    }
    out_ha_final[nd] = H;
    out_hs_final[nd] = sqrtf(V);
}

// ---------------------------------------------------------------------------
// K5 (primary): block = one fine segment (s in [0,256)), thread = d.
// All 16 n-chains live in registers (fully unrolled => no scratch).
// Per t the block writes the COMPLETE contiguous 64 KB row out[t][:][:] —
// each block is one sequential 1 MB write stream (DRAM open-row friendly),
// unlike the old 64KB-strided walk that thrashed the same banks from all
// 32 power-of-2-strided s-regions at once.
// ---------------------------------------------------------------------------
__global__ __launch_bounds__(512) void k5_lin(const float* __restrict__ x,
                                              const float* __restrict__ alpha,
                                              const float* __restrict__ haStart,
                                              const float* __restrict__ hvStart,
                                              float* __restrict__ out) {
    int s = blockIdx.x;                           // [0, SF_)
    int d = threadIdx.x;                          // [0, 512)
    float a[N_], cc[N_], ha[N_], hv[N_];
    #pragma unroll
    for (int n = 0; n < N_; ++n) {
        a[n]  = alpha[n * D_ + d];
        cc[n] = 1.0f - a[n];
        ha[n] = haStart[(size_t)s * ND_ + n * D_ + d];
        hv[n] = hvStart[(size_t)s * ND_ + n * D_ + d];
    }
    const float* xp = x + (size_t)s * LF_ * D_ + d;
    float* orow = out + (size_t)s * LF_ * 2 * ND_ + d;
    float xv = xp[0];
    for (int t = 0; t < LF_; ++t) {
        float xnext = (t + 1 < LF_) ? xp[(size_t)(t + 1) * D_] : 0.0f;  // prefetch
        float* oa = orow + (size_t)t * 2 * ND_;
        #pragma unroll
        for (int n = 0; n < N_; ++n) {
            float dd = xv - ha[n];
            hv[n] = cc[n] * fmaf(a[n], dd * dd, hv[n]);
            ha[n] = fmaf(a[n], dd, ha[n]);
            __builtin_nontemporal_store(ha[n], oa + n * D_);
            __builtin_nontemporal_store(__builtin_amdgcn_sqrtf(hv[n]), oa + ND_ + n * D_);
        }
        xv = xnext;
    }
}

// ---------------------------------------------------------------------------
// K5 (fallback, round-1 verified): per (s,n,d) thread, strided stores.
// ---------------------------------------------------------------------------
__global__ __launch_bounds__(256) void k5_fb(const float* __restrict__ x,
                                             const float* __restrict__ alpha,
                                             const float* __restrict__ haStart,
                                             const float* __restrict__ hvStart,
                                             float* __restrict__ out) {
    int bid  = blockIdx.x;
    int obid = (bid & 7) * 128 + (bid >> 3);
    int gid  = obid * 256 + threadIdx.x;
    int d    = gid & (D_ - 1);
    int n    = (gid >> 9) & (N_ - 1);
    int nd   = gid & (ND_ - 1);
    int s    = gid >> 13;
    float a  = alpha[nd];
    float c  = 1.0f - a;
    float ha = haStart[gid];
    float hv = hvStart[gid];
    const float* xp = x + (size_t)s * L_ * D_ + d;
    float* oa = out + (size_t)s * L_ * 2 * ND_ + (size_t)n * D_ + d;
    float* os = oa + ND_;
    #pragma unroll 4
    for (int t = 0; t < L_; ++t) {
        float xv = xp[(size_t)t * D_];
        float dd = xv - ha;
        hv = c * fmaf(a, dd * dd, hv);
        ha = fmaf(a, dd, ha);
        __builtin_nontemporal_store(ha, oa + (size_t)t * 2 * ND_);
        __builtin_nontemporal_store(__builtin_amdgcn_sqrtf(hv), os + (size_t)t * 2 * ND_);
    }
}

extern "C" void kernel_launch(void* const* d_in, const int* in_sizes, int n_in,
                              void* d_out, int out_size, void* d_ws, size_t ws_size,
                              hipStream_t stream) {
    const float* x     = (const float*)d_in[0];   // [T, D]
    const float* h_a   = (const float*)d_in[1];   // [N, D]
    const float* h_s   = (const float*)d_in[2];   // [N, D]
    const float* alpha = (const float*)d_in[3];   // [N, D]
    float* out = (float*)d_out;                   // [T, 2N, D] ++ ha_N ++ sqrt(hv_N)

    float* out_ha_final = out + (size_t)T_ * 2 * ND_;   // [N, D]
    float* out_hs_final = out_ha_final + ND_;           // [N, D]

    dim3 b256(256);
    float* ws = (float*)d_ws;

    if (ws_size >= (size_t)3 * SNDF_ * sizeof(float)) {
        // Primary: fine segmentation, row-linear output writes.
        float* P  = ws;                            // [SF, N, D] -> haStart
        float* Q0 = ws + (size_t)SNDF_;            // [SF, N, D] -> hvStart
        float* S1 = ws + 2 * (size_t)SNDF_;        // [SF, N, D]
        k1_seg<SF_, LF_, 1024><<<dim3(SNDF_ / 256), b256, 0, stream>>>(x, alpha, P, Q0, S1);
        k2_prefix<SF_, 4><<<dim3(ND_ / 256), b256, 0, stream>>>(h_a, h_s, alpha, P, Q0, S1,
                                                                out_ha_final, out_hs_final);
        k5_lin<<<dim3(SF_), dim3(512), 0, stream>>>(x, alpha, P, Q0, out);
    } else {
        // Fallback: round-1 verified pipeline (3 MiB workspace).
        float* P  = ws;
        float* Q0 = ws + (size_t)SND_;
        float* S1 = ws + 2 * (size_t)SND_;
        k1_seg<S_, L_, 128><<<dim3(SND_ / 256), b256, 0, stream>>>(x, alpha, P, Q0, S1);
        k2_prefix<S_, 7><<<dim3(ND_ / 256), b256, 0, stream>>>(h_a, h_s, alpha, P, Q0, S1,
                                                               out_ha_final, out_hs_final);
        k5_fb<<<dim3(SND_ / 256), b256, 0, stream>>>(x, alpha, P, Q0, out);
    }
}

// Round 3
// 295.693 us; speedup vs baseline: 1.1210x; 1.1210x over previous
//
#include <hip/hip_runtime.h>
#include <math.h>

// Problem constants: T=4096, N=16, D=512.
#define T_   4096
#define D_   512
#define N_   16
#define ND_  (N_*D_)       // 8192 chains

// Primary segmentation: 64 segments of 64 steps (vec4 kernels).
#define S_    64
#define L_    64
#define SND_  (S_*ND_)     // 524,288 -> 3 arrays = 6 MiB workspace
#define ND4_  (ND_/4)      // 2048 float4-chains
#define SND4_ (S_*ND4_)    // 131,072 vec4 threads

// Fallback segmentation (round-1 verified): 32 segments of 128, scalar.
#define SB_   32
#define LB_   128
#define SNDB_ (SB_*ND_)    // 262,144 -> 3 MiB workspace

typedef float f4 __attribute__((ext_vector_type(4)));

__device__ __forceinline__ f4 vfma(f4 a, f4 b, f4 c) {
    f4 r;
    r.x = fmaf(a.x, b.x, c.x);
    r.y = fmaf(a.y, b.y, c.y);
    r.z = fmaf(a.z, b.z, c.z);
    r.w = fmaf(a.w, b.w, c.w);
    return r;
}

// c^(2^K) by K squarings.
template <int K>
__device__ __forceinline__ float pow2k(float c) {
    float r = c;
    #pragma unroll
    for (int i = 0; i < K; ++i) r *= r;
    return r;
}

// ---------------------------------------------------------------------------
// K1 (vec4): per (s,n,d4) one pass over its segment with zero-init states.
//   P  = particular ha at segment end     (p' = p + a*(x-p))
//   Q0 = particular hv at segment end     (q' = c*(q + a*e^2), e = x-p)
//   S1 = sum of e_t
// 16B loads and stores; 4 independent chains per thread.
// ---------------------------------------------------------------------------
__global__ __launch_bounds__(256) void k1_seg_v4(const f4* __restrict__ x4,
                                                 const f4* __restrict__ alpha4,
                                                 f4* __restrict__ P4,
                                                 f4* __restrict__ Q04,
                                                 f4* __restrict__ S14) {
    int bid  = blockIdx.x;
    int obid = (bid & 7) * (SND4_ / 256 / 8) + (bid >> 3);   // XCD swizzle
    int gid  = obid * 256 + threadIdx.x;       // [0, SND4_)
    int nd4  = gid & (ND4_ - 1);
    int s    = gid >> 11;                      // / ND4_
    f4 a = alpha4[nd4];
    f4 c = 1.0f - a;
    f4 p = 0.0f, q = 0.0f, s1 = 0.0f;
    const f4* xp = x4 + (size_t)s * L_ * (D_ / 4) + (gid & (D_ / 4 - 1));
    #pragma unroll 8
    for (int t = 0; t < L_; ++t) {
        f4 xv = xp[(size_t)t * (D_ / 4)];
        f4 e  = xv - p;
        q  = c * vfma(a, e * e, q);
        p  = vfma(a, e, p);
        s1 += e;
    }
    P4[gid]  = p;
    Q04[gid] = q;
    S14[gid] = s1;
}

// ---------------------------------------------------------------------------
// K2: per (n,d) scan across segments for BOTH ha and hv; overwrites P with
// segment-start ha and Q0 with segment-start hv; writes finals.
//   hv_L = cL*hv0 + Q0 - 2*a*cL*S1*ha0 + cL*(1-cL)*ha0^2 ;  ha_L = cL*ha0 + P
// ---------------------------------------------------------------------------
template <int SS, int LOG2L>
__global__ __launch_bounds__(256) void k2_prefix(const float* __restrict__ h_a,
                                                 const float* __restrict__ h_s,
                                                 const float* __restrict__ alpha,
                                                 float* __restrict__ P,    // -> haStart
                                                 float* __restrict__ Q0,   // -> hvStart
                                                 const float* __restrict__ S1,
                                                 float* __restrict__ out_ha_final,
                                                 float* __restrict__ out_hs_final) {
    int nd   = blockIdx.x * 256 + threadIdx.x;    // [0, ND_)
    float a  = alpha[nd];
    float c  = 1.0f - a;
    float cL = pow2k<LOG2L>(c);
    float k1 = 2.0f * a * cL;
    float k2 = cL * (1.0f - cL);
    float H  = h_a[nd];
    float hs = h_s[nd];
    float V  = hs * hs;
    #pragma unroll 4
    for (int s = 0; s < SS; ++s) {
        size_t i = (size_t)s * ND_ + nd;
        float p  = P[i];
        float q  = Q0[i];
        float s1 = S1[i];
        P[i]  = H;
        Q0[i] = V;
        float Vn = cL * V + q - k1 * s1 * H + k2 * H * H;
        V = fmaxf(Vn, 0.0f);                      // guard cancellation (hv >= 0)
        H = fmaf(cL, H, p);
    }
    out_ha_final[nd] = H;
    out_hs_final[nd] = sqrtf(V);
}

// ---------------------------------------------------------------------------
// K5 (vec4): per (s,n,d4) thread runs the exact reference recurrence for 4
// consecutive d from correct start states. 16B x-loads, 16B NT stores —
// 1 KB per wave store instruction (the harness fill's width) vs the old 256 B.
// ---------------------------------------------------------------------------
__global__ __launch_bounds__(256) void k5_v4(const f4* __restrict__ x4,
                                             const f4* __restrict__ alpha4,
                                             const f4* __restrict__ haStart4,
                                             const f4* __restrict__ hvStart4,
                                             f4* __restrict__ out4) {
    int bid  = blockIdx.x;
    int obid = (bid & 7) * (SND4_ / 256 / 8) + (bid >> 3);   // XCD swizzle
    int gid  = obid * 256 + threadIdx.x;       // [0, SND4_)
    int d4   = gid & (D_ / 4 - 1);             // [0,128)
    int n    = (gid >> 7) & (N_ - 1);
    int nd4  = gid & (ND4_ - 1);
    int s    = gid >> 11;
    f4 a  = alpha4[nd4];
    f4 c  = 1.0f - a;
    f4 ha = haStart4[gid];
    f4 hv = hvStart4[gid];
    const f4* xp = x4 + (size_t)s * L_ * (D_ / 4) + d4;
    // out row for t=(s*L_+tt): float4 index (t*2*ND_ + n*D_)/4 + d4.
    f4* oa = out4 + (size_t)s * L_ * (2 * ND4_) + (size_t)n * (D_ / 4) + d4;
    #pragma unroll 4
    for (int t = 0; t < L_; ++t) {
        f4 xv = xp[(size_t)t * (D_ / 4)];
        f4 dd = xv - ha;
        hv = c * vfma(a, dd * dd, hv);
        ha = vfma(a, dd, ha);
        f4 sq;
        sq.x = __builtin_amdgcn_sqrtf(hv.x);
        sq.y = __builtin_amdgcn_sqrtf(hv.y);
        sq.z = __builtin_amdgcn_sqrtf(hv.z);
        sq.w = __builtin_amdgcn_sqrtf(hv.w);
        __builtin_nontemporal_store(ha, oa + (size_t)t * 2 * ND4_);
        __builtin_nontemporal_store(sq, oa + (size_t)t * 2 * ND4_ + ND4_);
    }
}

// ---------------------------------------------------------------------------
// Fallback (round-1 verified): scalar coarse pipeline, 3 MiB workspace.
// ---------------------------------------------------------------------------
__global__ __launch_bounds__(256) void k1_fb(const float* __restrict__ x,
                                             const float* __restrict__ alpha,
                                             float* __restrict__ P,
                                             float* __restrict__ Q0,
                                             float* __restrict__ S1) {
    int bid  = blockIdx.x;
    int obid = (bid & 7) * 128 + (bid >> 3);
    int gid  = obid * 256 + threadIdx.x;
    int d    = gid & (D_ - 1);
    int nd   = gid & (ND_ - 1);
    int s    = gid >> 13;
    float a  = alpha[nd];
    float c  = 1.0f - a;
    float p = 0.0f, q = 0.0f, s1 = 0.0f;
    const float* xp = x + (size_t)s * LB_ * D_ + d;
    #pragma unroll 8
    for (int t = 0; t < LB_; ++t) {
        float xv = xp[(size_t)t * D_];
        float e  = xv - p;
        q  = c * fmaf(a, e * e, q);
        p  = fmaf(a, e, p);
        s1 += e;
    }
    P[gid]  = p;
    Q0[gid] = q;
    S1[gid] = s1;
}

__global__ __launch_bounds__(256) void k5_fb(const float* __restrict__ x,
                                             const float* __restrict__ alpha,
                                             const float* __restrict__ haStart,
                                             const float* __restrict__ hvStart,
                                             float* __restrict__ out) {
    int bid  = blockIdx.x;
    int obid = (bid & 7) * 128 + (bid >> 3);
    int gid  = obid * 256 + threadIdx.x;
    int d    = gid & (D_ - 1);
    int n    = (gid >> 9) & (N_ - 1);
    int nd   = gid & (ND_ - 1);
    int s    = gid >> 13;
    float a  = alpha[nd];
    float c  = 1.0f - a;
    float ha = haStart[gid];
    float hv = hvStart[gid];
    const float* xp = x + (size_t)s * LB_ * D_ + d;
    float* oa = out + (size_t)s * LB_ * 2 * ND_ + (size_t)n * D_ + d;
    float* os = oa + ND_;
    #pragma unroll 4
    for (int t = 0; t < LB_; ++t) {
        float xv = xp[(size_t)t * D_];
        float dd = xv - ha;
        hv = c * fmaf(a, dd * dd, hv);
        ha = fmaf(a, dd, ha);
        __builtin_nontemporal_store(ha, oa + (size_t)t * 2 * ND_);
        __builtin_nontemporal_store(__builtin_amdgcn_sqrtf(hv), os + (size_t)t * 2 * ND_);
    }
}

extern "C" void kernel_launch(void* const* d_in, const int* in_sizes, int n_in,
                              void* d_out, int out_size, void* d_ws, size_t ws_size,
                              hipStream_t stream) {
    const float* x     = (const float*)d_in[0];   // [T, D]
    const float* h_a   = (const float*)d_in[1];   // [N, D]
    const float* h_s   = (const float*)d_in[2];   // [N, D]
    const float* alpha = (const float*)d_in[3];   // [N, D]
    float* out = (float*)d_out;                   // [T, 2N, D] ++ ha_N ++ sqrt(hv_N)

    float* out_ha_final = out + (size_t)T_ * 2 * ND_;   // [N, D]
    float* out_hs_final = out_ha_final + ND_;           // [N, D]

    dim3 b256(256);
    float* ws = (float*)d_ws;

    if (ws_size >= (size_t)3 * SND_ * sizeof(float)) {
        // Primary: S=64/L=64, vec4 loads/stores throughout the heavy kernels.
        float* P  = ws;                            // [S, N, D] -> haStart
        float* Q0 = ws + (size_t)SND_;             // [S, N, D] -> hvStart
        float* S1 = ws + 2 * (size_t)SND_;         // [S, N, D]
        k1_seg_v4<<<dim3(SND4_ / 256), b256, 0, stream>>>(
            (const f4*)x, (const f4*)alpha, (f4*)P, (f4*)Q0, (f4*)S1);
        k2_prefix<S_, 6><<<dim3(ND_ / 256), b256, 0, stream>>>(
            h_a, h_s, alpha, P, Q0, S1, out_ha_final, out_hs_final);
        k5_v4<<<dim3(SND4_ / 256), b256, 0, stream>>>(
            (const f4*)x, (const f4*)alpha, (const f4*)P, (const f4*)Q0, (f4*)out);
    } else {
        // Fallback: round-1 verified pipeline (3 MiB workspace).
        float* P  = ws;
        float* Q0 = ws + (size_t)SNDB_;
        float* S1 = ws + 2 * (size_t)SNDB_;
        k1_fb<<<dim3(SNDB_ / 256), b256, 0, stream>>>(x, alpha, P, Q0, S1);
        k2_prefix<SB_, 7><<<dim3(ND_ / 256), b256, 0, stream>>>(
            h_a, h_s, alpha, P, Q0, S1, out_ha_final, out_hs_final);
        k5_fb<<<dim3(SNDB_ / 256), b256, 0, stream>>>(x, alpha, P, Q0, out);
    }
}

// Round 4
// 288.466 us; speedup vs baseline: 1.1491x; 1.0251x over previous
//
#include <hip/hip_runtime.h>
#include <math.h>

// Problem constants: T=4096, N=16, D=512.
#define T_   4096
#define D_   512
#define N_   16
#define ND_  (N_*D_)       // 8192 chains

// Primary segmentation: 64 segments of 64 steps (vec4 kernels).
#define S_    64
#define L_    64
#define SND_  (S_*ND_)     // 524,288 -> 3 arrays = 6 MiB workspace
#define ND4_  (ND_/4)      // 2048 float4-chains
#define SND4_ (S_*ND4_)    // 131,072 vec4 threads

// Fallback segmentation (round-1 verified): 32 segments of 128, scalar.
#define SB_   32
#define LB_   128
#define SNDB_ (SB_*ND_)    // 262,144 -> 3 MiB workspace

typedef float f4 __attribute__((ext_vector_type(4)));

__device__ __forceinline__ f4 vfma(f4 a, f4 b, f4 c) {
    f4 r;
    r.x = fmaf(a.x, b.x, c.x);
    r.y = fmaf(a.y, b.y, c.y);
    r.z = fmaf(a.z, b.z, c.z);
    r.w = fmaf(a.w, b.w, c.w);
    return r;
}

// c^(2^K) by K squarings.
template <int K>
__device__ __forceinline__ float pow2k(float c) {
    float r = c;
    #pragma unroll
    for (int i = 0; i < K; ++i) r *= r;
    return r;
}

// ---------------------------------------------------------------------------
// K1 (vec4): per (s,n,d4) one pass over its segment with zero-init states.
//   P  = particular ha at segment end     (p' = p + a*(x-p))
//   Q0 = particular hv at segment end     (q' = c*(q + a*e^2), e = x-p)
//   S1 = sum of e_t
// ---------------------------------------------------------------------------
__global__ __launch_bounds__(256) void k1_seg_v4(const f4* __restrict__ x4,
                                                 const f4* __restrict__ alpha4,
                                                 f4* __restrict__ P4,
                                                 f4* __restrict__ Q04,
                                                 f4* __restrict__ S14) {
    int bid  = blockIdx.x;
    int obid = (bid & 7) * (SND4_ / 256 / 8) + (bid >> 3);   // XCD swizzle
    int gid  = obid * 256 + threadIdx.x;       // [0, SND4_)
    int nd4  = gid & (ND4_ - 1);
    int s    = gid >> 11;                      // / ND4_
    f4 a = alpha4[nd4];
    f4 c = 1.0f - a;
    f4 p = 0.0f, q = 0.0f, s1 = 0.0f;
    const f4* xp = x4 + (size_t)s * L_ * (D_ / 4) + (gid & (D_ / 4 - 1));
    #pragma unroll 8
    for (int t = 0; t < L_; ++t) {
        f4 xv = xp[(size_t)t * (D_ / 4)];
        f4 e  = xv - p;
        q  = c * vfma(a, e * e, q);
        p  = vfma(a, e, p);
        s1 += e;
    }
    P4[gid]  = p;
    Q04[gid] = q;
    S14[gid] = s1;
}

// ---------------------------------------------------------------------------
// K2: per (n,d) scan across segments for BOTH ha and hv; overwrites P with
// segment-start ha and Q0 with segment-start hv; writes finals.
//   hv_L = cL*hv0 + Q0 - 2*a*cL*S1*ha0 + cL*(1-cL)*ha0^2 ;  ha_L = cL*ha0 + P
// ---------------------------------------------------------------------------
template <int SS, int LOG2L>
__global__ __launch_bounds__(256) void k2_prefix(const float* __restrict__ h_a,
                                                 const float* __restrict__ h_s,
                                                 const float* __restrict__ alpha,
                                                 float* __restrict__ P,    // -> haStart
                                                 float* __restrict__ Q0,   // -> hvStart
                                                 const float* __restrict__ S1,
                                                 float* __restrict__ out_ha_final,
                                                 float* __restrict__ out_hs_final) {
    int nd   = blockIdx.x * 256 + threadIdx.x;    // [0, ND_)
    float a  = alpha[nd];
    float c  = 1.0f - a;
    float cL = pow2k<LOG2L>(c);
    float k1 = 2.0f * a * cL;
    float k2 = cL * (1.0f - cL);
    float H  = h_a[nd];
    float hs = h_s[nd];
    float V  = hs * hs;
    #pragma unroll 4
    for (int s = 0; s < SS; ++s) {
        size_t i = (size_t)s * ND_ + nd;
        float p  = P[i];
        float q  = Q0[i];
        float s1 = S1[i];
        P[i]  = H;
        Q0[i] = V;
        float Vn = cL * V + q - k1 * s1 * H + k2 * H * H;
        V = fmaxf(Vn, 0.0f);                      // guard cancellation (hv >= 0)
        H = fmaf(cL, H, p);
    }
    out_ha_final[nd] = H;
    out_hs_final[nd] = sqrtf(V);
}

// ---------------------------------------------------------------------------
// K5 (vec4, PLAIN stores): per (s,n,d4) thread runs the exact reference
// recurrence for 4 consecutive d. Identical to round 3 except the stores are
// normal (cached) instead of non-temporal — isolating the NT flag, which is
// the last structural difference vs the 6.5 TB/s harness fill kernel.
// ---------------------------------------------------------------------------
__global__ __launch_bounds__(256) void k5_v4(const f4* __restrict__ x4,
                                             const f4* __restrict__ alpha4,
                                             const f4* __restrict__ haStart4,
                                             const f4* __restrict__ hvStart4,
                                             f4* __restrict__ out4) {
    int bid  = blockIdx.x;
    int obid = (bid & 7) * (SND4_ / 256 / 8) + (bid >> 3);   // XCD swizzle
    int gid  = obid * 256 + threadIdx.x;       // [0, SND4_)
    int d4   = gid & (D_ / 4 - 1);             // [0,128)
    int n    = (gid >> 7) & (N_ - 1);
    int nd4  = gid & (ND4_ - 1);
    int s    = gid >> 11;
    f4 a  = alpha4[nd4];
    f4 c  = 1.0f - a;
    f4 ha = haStart4[gid];
    f4 hv = hvStart4[gid];
    const f4* xp = x4 + (size_t)s * L_ * (D_ / 4) + d4;
    f4* oa = out4 + (size_t)s * L_ * (2 * ND4_) + (size_t)n * (D_ / 4) + d4;
    #pragma unroll 4
    for (int t = 0; t < L_; ++t) {
        f4 xv = xp[(size_t)t * (D_ / 4)];
        f4 dd = xv - ha;
        hv = c * vfma(a, dd * dd, hv);
        ha = vfma(a, dd, ha);
        f4 sq;
        sq.x = __builtin_amdgcn_sqrtf(hv.x);
        sq.y = __builtin_amdgcn_sqrtf(hv.y);
        sq.z = __builtin_amdgcn_sqrtf(hv.z);
        sq.w = __builtin_amdgcn_sqrtf(hv.w);
        oa[(size_t)t * 2 * ND4_]        = ha;   // plain store
        oa[(size_t)t * 2 * ND4_ + ND4_] = sq;   // plain store
    }
}

// ---------------------------------------------------------------------------
// Fallback (round-1 verified): scalar coarse pipeline, 3 MiB workspace.
// ---------------------------------------------------------------------------
__global__ __launch_bounds__(256) void k1_fb(const float* __restrict__ x,
                                             const float* __restrict__ alpha,
                                             float* __restrict__ P,
                                             float* __restrict__ Q0,
                                             float* __restrict__ S1) {
    int bid  = blockIdx.x;
    int obid = (bid & 7) * 128 + (bid >> 3);
    int gid  = obid * 256 + threadIdx.x;
    int d    = gid & (D_ - 1);
    int nd   = gid & (ND_ - 1);
    int s    = gid >> 13;
    float a  = alpha[nd];
    float c  = 1.0f - a;
    float p = 0.0f, q = 0.0f, s1 = 0.0f;
    const float* xp = x + (size_t)s * LB_ * D_ + d;
    #pragma unroll 8
    for (int t = 0; t < LB_; ++t) {
        float xv = xp[(size_t)t * D_];
        float e  = xv - p;
        q  = c * fmaf(a, e * e, q);
        p  = fmaf(a, e, p);
        s1 += e;
    }
    P[gid]  = p;
    Q0[gid] = q;
    S1[gid] = s1;
}

__global__ __launch_bounds__(256) void k5_fb(const float* __restrict__ x,
                                             const float* __restrict__ alpha,
                                             const float* __restrict__ haStart,
                                             const float* __restrict__ hvStart,
                                             float* __restrict__ out) {
    int bid  = blockIdx.x;
    int obid = (bid & 7) * 128 + (bid >> 3);
    int gid  = obid * 256 + threadIdx.x;
    int d    = gid & (D_ - 1);
    int n    = (gid >> 9) & (N_ - 1);
    int nd   = gid & (ND_ - 1);
    int s    = gid >> 13;
    float a  = alpha[nd];
    float c  = 1.0f - a;
    float ha = haStart[gid];
    float hv = hvStart[gid];
    const float* xp = x + (size_t)s * LB_ * D_ + d;
    float* oa = out + (size_t)s * LB_ * 2 * ND_ + (size_t)n * D_ + d;
    float* os = oa + ND_;
    #pragma unroll 4
    for (int t = 0; t < LB_; ++t) {
        float xv = xp[(size_t)t * D_];
        float dd = xv - ha;
        hv = c * fmaf(a, dd * dd, hv);
        ha = fmaf(a, dd, ha);
        oa[(size_t)t * 2 * ND_] = ha;
        os[(size_t)t * 2 * ND_] = __builtin_amdgcn_sqrtf(hv);
    }
}

extern "C" void kernel_launch(void* const* d_in, const int* in_sizes, int n_in,
                              void* d_out, int out_size, void* d_ws, size_t ws_size,
                              hipStream_t stream) {
    const float* x     = (const float*)d_in[0];   // [T, D]
    const float* h_a   = (const float*)d_in[1];   // [N, D]
    const float* h_s   = (const float*)d_in[2];   // [N, D]
    const float* alpha = (const float*)d_in[3];   // [N, D]
    float* out = (float*)d_out;                   // [T, 2N, D] ++ ha_N ++ sqrt(hv_N)

    float* out_ha_final = out + (size_t)T_ * 2 * ND_;   // [N, D]
    float* out_hs_final = out_ha_final + ND_;           // [N, D]

    dim3 b256(256);
    float* ws = (float*)d_ws;

    if (ws_size >= (size_t)3 * SND_ * sizeof(float)) {
        // Primary: S=64/L=64, vec4 loads/stores, plain (cached) output stores.
        float* P  = ws;                            // [S, N, D] -> haStart
        float* Q0 = ws + (size_t)SND_;             // [S, N, D] -> hvStart
        float* S1 = ws + 2 * (size_t)SND_;         // [S, N, D]
        k1_seg_v4<<<dim3(SND4_ / 256), b256, 0, stream>>>(
            (const f4*)x, (const f4*)alpha, (f4*)P, (f4*)Q0, (f4*)S1);
        k2_prefix<S_, 6><<<dim3(ND_ / 256), b256, 0, stream>>>(
            h_a, h_s, alpha, P, Q0, S1, out_ha_final, out_hs_final);
        k5_v4<<<dim3(SND4_ / 256), b256, 0, stream>>>(
            (const f4*)x, (const f4*)alpha, (const f4*)P, (const f4*)Q0, (f4*)out);
    } else {
        // Fallback: round-1 verified pipeline (3 MiB workspace).
        float* P  = ws;
        float* Q0 = ws + (size_t)SNDB_;
        float* S1 = ws + 2 * (size_t)SNDB_;
        k1_fb<<<dim3(SNDB_ / 256), b256, 0, stream>>>(x, alpha, P, Q0, S1);
        k2_prefix<SB_, 7><<<dim3(ND_ / 256), b256, 0, stream>>>(
            h_a, h_s, alpha, P, Q0, S1, out_ha_final, out_hs_final);
        k5_fb<<<dim3(SNDB_ / 256), b256, 0, stream>>>(x, alpha, P, Q0, out);
    }
}